// Round 5
// baseline (432.345 us; speedup 1.0000x reference)
//
#include <hip/hip_runtime.h>
#include <math.h>

#define NPTS 4096
#define BLK 128
#define V 32
#define NPROJ 256
#define NBATCH 32

// V=32 floats/thread, BLK=128. Three register layouts (regs always include
// idx bits [1:0] so ALL LDS traffic is float4/b128):
//   A: regs = idx[4:0]          thread T_A = idx[11:5]
//   B: regs = {idx[7:5],[1:0]}  thread T_B = {idx[11:8], idx[4:2]}
//   C: regs = {idx[10:8],[1:0]} thread T_C = {idx[11],  idx[7:2]}
// Placement rule (every phase): element -> float4 slot  T*8 + (C ^ (T&7))
// where C = the layout's 3 chunk bits. Bank-even for every read/write side
// (8 dwords/bank per b128 = the hardware optimum).
// Normalized bitonic: each merge starts with reversal pairing i <-> i^(m-1)
// fused into LDS reads (partner chunk = own ^ const, reversed components);
// all remaining stages are ascending min/max.

__device__ __forceinline__ void cmpex_asc(float& a, float& b) {
    const float lo = fminf(a, b), hi = fmaxf(a, b);
    a = lo; b = hi;
}

// Ascending cleaner stages JB down to JL over the 32 registers.
template<int JB, int JL>
__device__ __forceinline__ void stages(float* v) {
#pragma unroll
    for (int r = 0; r < V; ++r)
        if ((r & JB) == 0) cmpex_asc(v[r], v[r | JB]);
    if constexpr (JB > JL) stages<(JB >> 1), JL>(v);
}

// In-register reversal for merge size MASK+1 (MASK <= 31).
template<int MASK>
__device__ __forceinline__ void rev_inreg(float* v) {
    constexpr int S = (MASK + 1) >> 1;
#pragma unroll
    for (int r = 0; r < V; ++r) {
        if ((r & S) == 0) {
            const float a = v[r], b = v[r ^ MASK];
            v[r] = fminf(a, b);
            v[r ^ MASK] = fmaxf(a, b);
        }
    }
}

// ---- LDS access helpers (all float4). s = base of 4096-float buffer ----

// Write own registers at this layout's natural (own) slots.
__device__ __forceinline__ void write_own(float* s, const float* v, int t) {
    float4* s4 = (float4*)s;
    const int ob = t << 3, o7 = t & 7;
#pragma unroll
    for (int c = 0; c < 8; ++c)
        s4[ob | (c ^ o7)] = make_float4(v[4*c], v[4*c+1], v[4*c+2], v[4*c+3]);
}
// Read own slots.
__device__ __forceinline__ void read_own(const float* s, float* v, int t) {
    const float4* s4 = (const float4*)s;
    const int ob = t << 3, o7 = t & 7;
#pragma unroll
    for (int c = 0; c < 8; ++c) {
        const float4 f = s4[ob | (c ^ o7)];
        v[4*c] = f.x; v[4*c+1] = f.y; v[4*c+2] = f.z; v[4*c+3] = f.w;
    }
}
// Scatter write: slot = base | (c<<3) | (q ^ c).  A->B, B->A (base=sAB,q=t7),
// A->C (base=sAC, q=t37).
__device__ __forceinline__ void write_sc(float* s, const float* v, int base, int q) {
    float4* s4 = (float4*)s;
#pragma unroll
    for (int c = 0; c < 8; ++c)
        s4[base | (c << 3) | (q ^ c)] = make_float4(v[4*c], v[4*c+1], v[4*c+2], v[4*c+3]);
}
// C->B scatter: slot = sCB | (c<<6)  (quad folded into sCB).
__device__ __forceinline__ void write_CB(float* s, const float* v, int sCB) {
    float4* s4 = (float4*)s;
#pragma unroll
    for (int c = 0; c < 8; ++c)
        s4[sCB | (c << 6)] = make_float4(v[4*c], v[4*c+1], v[4*c+2], v[4*c+3]);
}
// Layout-entry read with fused reversal: own chunk + partner chunk (thread
// t^TM, chunk c^CM, components reversed). Keep side: chunk bit KB (compile-
// time) or thread-uniform tmax when KB==0.
template<int TM, int CM, int KB>
__device__ __forceinline__ void read_rev(const float* s, float* v, int t, bool tmax) {
    const float4* s4 = (const float4*)s;
    const int ob = t << 3, o7 = t & 7;
    const int pt = t ^ TM;
    const int pb = pt << 3, p7 = pt & 7;
#pragma unroll
    for (int c = 0; c < 8; ++c) {
        const float4 o = s4[ob | (c ^ o7)];
        const float4 q = s4[pb | ((c ^ CM) ^ p7)];
        const bool mx = KB ? ((c & KB) != 0) : tmax;
        v[4*c+0] = mx ? fmaxf(o.x, q.w) : fminf(o.x, q.w);
        v[4*c+1] = mx ? fmaxf(o.y, q.z) : fminf(o.y, q.z);
        v[4*c+2] = mx ? fmaxf(o.z, q.y) : fminf(o.z, q.y);
        v[4*c+3] = mx ? fmaxf(o.w, q.x) : fminf(o.w, q.x);
    }
}
// Merge-64 reversal: own data already in A-regs; read partner row only.
__device__ __forceinline__ void rev_partner64(const float* s, float* v, int t) {
    const float4* s4 = (const float4*)s;
    const int pt = t ^ 1, pb = pt << 3, p7 = pt & 7;
    const bool mx = (t & 1) != 0;
#pragma unroll
    for (int c = 0; c < 8; ++c) {
        const float4 q = s4[pb | ((c ^ 7) ^ p7)];
        v[4*c+0] = mx ? fmaxf(v[4*c+0], q.w) : fminf(v[4*c+0], q.w);
        v[4*c+1] = mx ? fmaxf(v[4*c+1], q.z) : fminf(v[4*c+1], q.z);
        v[4*c+2] = mx ? fmaxf(v[4*c+2], q.y) : fminf(v[4*c+2], q.y);
        v[4*c+3] = mx ? fmaxf(v[4*c+3], q.x) : fminf(v[4*c+3], q.x);
    }
}

__global__ __launch_bounds__(BLK, 3) void swd_kernel(
    const float* __restrict__ x, const float* __restrict__ y,
    const float* __restrict__ theta, const float* __restrict__ rot,
    float* __restrict__ per_batch) {
    __shared__ float xs[NPTS];
    __shared__ float ys[NPTS];

    const int t = threadIdx.x;   // 0..127
    const int p = blockIdx.x;
    const int b = blockIdx.y;

    const float t0 = theta[p * 3 + 0], t1 = theta[p * 3 + 1], t2 = theta[p * 3 + 2];
    const float* R = rot + b * 9;
    const float p0 = t0 * R[0] + t1 * R[3] + t2 * R[6];
    const float p1 = t0 * R[1] + t1 * R[4] + t2 * R[7];
    const float p2 = t0 * R[2] + t1 * R[5] + t2 * R[8];

    // Load 32 points each (A layout: idx = t*32 + r), project.
    float vx[V], vy[V];
    {
        const float4* xb4 = (const float4*)(x + (size_t)b * NPTS * 3 + (size_t)t * V * 3);
        const float4* yb4 = (const float4*)(y + (size_t)b * NPTS * 3 + (size_t)t * V * 3);
#pragma unroll
        for (int g = 0; g < 8; ++g) {
            float4 a = xb4[g * 3 + 0], c = xb4[g * 3 + 1], d = xb4[g * 3 + 2];
            vx[4*g+0] = a.x * p0 + a.y * p1 + a.z * p2;
            vx[4*g+1] = a.w * p0 + c.x * p1 + c.y * p2;
            vx[4*g+2] = c.z * p0 + c.w * p1 + d.x * p2;
            vx[4*g+3] = d.y * p0 + d.z * p1 + d.w * p2;
            a = yb4[g * 3 + 0]; c = yb4[g * 3 + 1]; d = yb4[g * 3 + 2];
            vy[4*g+0] = a.x * p0 + a.y * p1 + a.z * p2;
            vy[4*g+1] = a.w * p0 + c.x * p1 + c.y * p2;
            vy[4*g+2] = c.z * p0 + c.w * p1 + d.x * p2;
            vy[4*g+3] = d.y * p0 + d.z * p1 + d.w * p2;
        }
    }

    // Scatter bases.
    const int t7  = t & 7;
    const int t37 = (t >> 3) & 7;
    const int sAB = (t & 0x78) << 3;                            // A<->B
    const int sAC = ((t & 0x40) << 3) | (t7 << 6);              // A->C
    const int sCB = ((t >> 6) << 9) | (t7 << 3) | (t37 ^ t7);   // C->B

#define SYNC __syncthreads();
#define BOTH(OP) OP(xs, vx); OP(ys, vy);

    // ---- merges 2..32: fully in-register ----
    rev_inreg<1>(vx);  rev_inreg<1>(vy);
    rev_inreg<3>(vx);  rev_inreg<3>(vy);  stages<1,1>(vx); stages<1,1>(vy);
    rev_inreg<7>(vx);  rev_inreg<7>(vy);  stages<2,1>(vx); stages<2,1>(vy);
    rev_inreg<15>(vx); rev_inreg<15>(vy); stages<4,1>(vx); stages<4,1>(vy);
    rev_inreg<31>(vx); rev_inreg<31>(vy); stages<8,1>(vx); stages<8,1>(vy);

    // ---- merge 64: A-write, partner-row read (rev), cleaners in A ----
    write_own(xs, vx, t); write_own(ys, vy, t); SYNC
    rev_partner64(xs, vx, t); rev_partner64(ys, vy, t); SYNC
    stages<16,1>(vx); stages<16,1>(vy);

    // ---- merge 128: rev in B (TM=7,CM=3,keep=cb&2), j=32 in B, tail in A ----
    write_sc(xs, vx, sAB, t7); write_sc(ys, vy, sAB, t7); SYNC
    read_rev<7,3,2>(xs, vx, t, false); read_rev<7,3,2>(ys, vy, t, false); SYNC
    stages<4,4>(vx); stages<4,4>(vy);
    write_sc(xs, vx, sAB, t7); write_sc(ys, vy, sAB, t7); SYNC
    read_own(xs, vx, t); read_own(ys, vy, t); SYNC
    stages<16,1>(vx); stages<16,1>(vy);

    // ---- merge 256: rev in B (TM=7,CM=7,keep=cb&4), j=64,32 in B ----
    write_sc(xs, vx, sAB, t7); write_sc(ys, vy, sAB, t7); SYNC
    read_rev<7,7,4>(xs, vx, t, false); read_rev<7,7,4>(ys, vy, t, false); SYNC
    stages<8,4>(vx); stages<8,4>(vy);
    write_sc(xs, vx, sAB, t7); write_sc(ys, vy, sAB, t7); SYNC
    read_own(xs, vx, t); read_own(ys, vy, t); SYNC
    stages<16,1>(vx); stages<16,1>(vy);

    // ---- merge 512: rev in B (TM=15,CM=7,keep=t&8), j=128,64,32 in B ----
    write_sc(xs, vx, sAB, t7); write_sc(ys, vy, sAB, t7); SYNC
    {
        const bool km = (t & 8) != 0;
        read_rev<15,7,0>(xs, vx, t, km); read_rev<15,7,0>(ys, vy, t, km);
    }
    SYNC
    stages<16,4>(vx); stages<16,4>(vy);
    write_sc(xs, vx, sAB, t7); write_sc(ys, vy, sAB, t7); SYNC
    read_own(xs, vx, t); read_own(ys, vy, t); SYNC
    stages<16,1>(vx); stages<16,1>(vy);

    // ---- merge 1024: rev in C (TM=63,CM=3,keep=cc&2), j=256 in C; B; A ----
    write_sc(xs, vx, sAC, t37); write_sc(ys, vy, sAC, t37); SYNC
    read_rev<63,3,2>(xs, vx, t, false); read_rev<63,3,2>(ys, vy, t, false); SYNC
    stages<4,4>(vx); stages<4,4>(vy);
    write_CB(xs, vx, sCB); write_CB(ys, vy, sCB); SYNC
    read_own(xs, vx, t); read_own(ys, vy, t); SYNC
    stages<16,4>(vx); stages<16,4>(vy);
    write_sc(xs, vx, sAB, t7); write_sc(ys, vy, sAB, t7); SYNC
    read_own(xs, vx, t); read_own(ys, vy, t); SYNC
    stages<16,1>(vx); stages<16,1>(vy);

    // ---- merge 2048: rev in C (TM=63,CM=7,keep=cc&4), j=512,256 in C ----
    write_sc(xs, vx, sAC, t37); write_sc(ys, vy, sAC, t37); SYNC
    read_rev<63,7,4>(xs, vx, t, false); read_rev<63,7,4>(ys, vy, t, false); SYNC
    stages<8,4>(vx); stages<8,4>(vy);
    write_CB(xs, vx, sCB); write_CB(ys, vy, sCB); SYNC
    read_own(xs, vx, t); read_own(ys, vy, t); SYNC
    stages<16,4>(vx); stages<16,4>(vy);
    write_sc(xs, vx, sAB, t7); write_sc(ys, vy, sAB, t7); SYNC
    read_own(xs, vx, t); read_own(ys, vy, t); SYNC
    stages<16,1>(vx); stages<16,1>(vy);

    // ---- merge 4096: rev in C (TM=127,CM=7,keep=t&64), j=1024,512,256 in C ----
    write_sc(xs, vx, sAC, t37); write_sc(ys, vy, sAC, t37); SYNC
    {
        const bool km = (t & 64) != 0;
        read_rev<127,7,0>(xs, vx, t, km); read_rev<127,7,0>(ys, vy, t, km);
    }
    SYNC
    stages<16,4>(vx); stages<16,4>(vy);
    write_CB(xs, vx, sCB); write_CB(ys, vy, sCB); SYNC
    read_own(xs, vx, t); read_own(ys, vy, t); SYNC
    stages<16,4>(vx); stages<16,4>(vy);
    write_sc(xs, vx, sAB, t7); write_sc(ys, vy, sAB, t7); SYNC
    read_own(xs, vx, t); read_own(ys, vy, t); SYNC
    stages<16,1>(vx); stages<16,1>(vy);

    // Sorted ascending in A layout. Sum squared differences.
    float s = 0.0f;
#pragma unroll
    for (int r = 0; r < V; ++r) {
        const float d = vx[r] - vy[r];
        s += d * d;
    }
    for (int off = 32; off > 0; off >>= 1) s += __shfl_down(s, off, 64);
    SYNC  // xs free for reuse
    const int lane = t & 63, wave = t >> 6;
    if (lane == 0) xs[wave] = s;
    SYNC
    if (t == 0) atomicAdd(&per_batch[b], xs[0] + xs[1]);
}

__global__ void finalize_kernel(const float* __restrict__ per_batch, float* __restrict__ out) {
    const int t = threadIdx.x;  // 64 threads
    float v = (t < NBATCH) ? sqrtf(per_batch[t] * (1.0f / (float)NPROJ)) : 0.0f;
    for (int off = 32; off > 0; off >>= 1) v += __shfl_down(v, off, 64);
    if (t == 0) out[0] = v * (1.0f / (float)NBATCH);
}

extern "C" void kernel_launch(void* const* d_in, const int* in_sizes, int n_in,
                              void* d_out, int out_size, void* d_ws, size_t ws_size,
                              hipStream_t stream) {
    const float* x = (const float*)d_in[0];
    const float* y = (const float*)d_in[1];
    const float* theta = (const float*)d_in[2];
    const float* rot = (const float*)d_in[3];
    float* per_batch = (float*)d_ws;
    float* out = (float*)d_out;

    hipMemsetAsync(per_batch, 0, NBATCH * sizeof(float), stream);

    dim3 grid(NPROJ, NBATCH);
    swd_kernel<<<grid, BLK, 0, stream>>>(x, y, theta, rot, per_batch);

    finalize_kernel<<<1, 64, 0, stream>>>(per_batch, out);
}